// Round 8
// baseline (88.320 us; speedup 1.0000x reference)
//
#include <hip/hip_runtime.h>
#include <hip/hip_fp16.h>

#define SPAN 20
#define REPEAT 90

// pred, gt: [4, 1, 512, 512] f32. h_offsets, w_offsets: [90] i32.
// out: scalar f32 = mean |l2norm(pred_rd) - l2norm(gt_rd)| over [B,Hb,Wb,R].

constexpr int W  = 512;
constexpr int Wb = 472;           // 512 - 2*SPAN
constexpr int TJ = 64;            // output tile width  (j)
constexpr int TI = 8;             // output tile height (i); 472/8 = 59 exact
constexpr int TW = TJ + 2 * SPAN; // 104 input tile width
constexpr int TH = TI + 2 * SPAN; // 48  input tile height
constexpr int QW = TW / 2;        // 52 pairs per row
constexpr int PLANE = TH * QW;    // 2496 8B elements per plane

typedef unsigned int u32;

static __device__ __forceinline__ u32 packpg(float p, float g) {
    const __half2 h = __floats2half2_rn(p, g);
    return __builtin_bit_cast(u32, h);
}
static __device__ __forceinline__ __half2 h2(u32 v) {
    return __builtin_bit_cast(__half2, v);
}

__global__ __launch_bounds__(256, 4) void rd_loss_kernel(
    const float* __restrict__ pred, const float* __restrict__ gt,
    const int* __restrict__ hoff, const int* __restrict__ woff,
    float* __restrict__ out)
{
    // Parity-duplicated pair planes: plane[pi] pair q = {x[2q+pi], x[2q+1+pi]}
    // with x = {p,g} packed as half2 in one u32. Any (hoff,woff) shift becomes
    // an ALIGNED contiguous ds_read_b64 from plane[woff&1]. 2*2496*8 = 39936 B.
    // NO unions anywhere: round 7's union temporaries were demoted to scratch
    // (124 MB/launch of HBM scratch traffic); uint2 + bit_cast stays in VGPRs.
    __shared__ uint2 plane[2][PLANE];
    __shared__ float wsum[4];

    const int t  = threadIdx.x;
    const int bx = blockIdx.x;    // 0..7   j-tile
    const int by = blockIdx.y;    // 0..58  i-tile
    const int b  = blockIdx.z;    // 0..3   batch
    const int I0 = by * TI;
    const int J0 = bx * TJ;

    const float* pb_ = pred + b * (W * W);
    const float* gb_ = gt   + b * (W * W);

    // ---- stage both planes (rows always in range; cols clamped to 510,
    //      clamped junk only feeds masked-out pixels) ----
    for (int e = t; e < PLANE; e += 256) {
        const int row = e / QW;           // magic-mul div
        const int q   = e - row * QW;
        const int gr  = I0 + row;                       // <= 511 always
        int c0 = J0 + 2 * q;  c0 = c0 < 510 ? c0 : 510; // even -> float2 ok
        int c2 = c0 + 2;      c2 = c2 < 510 ? c2 : 510;
        const float2 pLo = *(const float2*)(pb_ + gr * W + c0);
        const float2 gLo = *(const float2*)(gb_ + gr * W + c0);
        const float2 pHi = *(const float2*)(pb_ + gr * W + c2);
        const float2 gHi = *(const float2*)(gb_ + gr * W + c2);
        const u32 h0 = packpg(pLo.x, gLo.x);   // x[2q]
        const u32 h1 = packpg(pLo.y, gLo.y);   // x[2q+1]
        const u32 hx = packpg(pHi.x, gHi.x);   // x[2q+2]
        plane[0][e] = make_uint2(h0, h1);
        plane[1][e] = make_uint2(h1, hx);
    }
    __syncthreads();

    // ---- 2 pixels per thread: (row, 2*jp) and (row, 2*jp+1) ----
    const int jp  = t & 31;               // pair 0..31
    const int row = t >> 5;               // 0..7
    const bool ok0 = (J0 + 2 * jp)     < Wb;
    const bool ok1 = (J0 + 2 * jp + 1) < Wb;

    const int lanebase = row * QW + jp;   // per-lane element index part
    const uint2 cc = plane[0][(SPAN + row) * QW + (SPAN / 2 + jp)];
    const __half2 c0 = h2(cc.x), c1 = h2(cc.y);

    // ---- pass 1: packed sum-of-squares, even/odd split accumulators ----
    __half2 sA0 = __floats2half2_rn(0.f, 0.f), sB0 = sA0;
    __half2 sA1 = sA0, sB1 = sA0;
    #pragma unroll
    for (int r = 0; r < REPEAT; ++r) {
        const int ho = hoff[r], wo = woff[r];          // uniform (s_load)
        const int pi = wo & 1;
        const int uo = (SPAN + ho) * QW + ((SPAN + wo - pi) >> 1);
        const uint2 vv = plane[pi][lanebase + uo];     // aligned b64
        const __half2 d0 = __hsub2(c0, h2(vv.x));
        const __half2 d1 = __hsub2(c1, h2(vv.y));
        if (r & 1) { sB0 = __hfma2(d0, d0, sB0); sB1 = __hfma2(d1, d1, sB1); }
        else       { sA0 = __hfma2(d0, d0, sA0); sA1 = __hfma2(d1, d1, sA1); }
    }
    const float ssp0 = __half2float(__low2half(sA0))  + __half2float(__low2half(sB0));
    const float ssg0 = __half2float(__high2half(sA0)) + __half2float(__high2half(sB0));
    const float ssp1 = __half2float(__low2half(sA1))  + __half2float(__low2half(sB1));
    const float ssg1 = __half2float(__high2half(sA1)) + __half2float(__high2half(sB1));

    const float invp0 = (ssp0 == 0.f) ? 1.f : rsqrtf(ssp0);
    const float invg0 = (ssg0 == 0.f) ? 1.f : rsqrtf(ssg0);
    const float invp1 = (ssp1 == 0.f) ? 1.f : rsqrtf(ssp1);
    const float invg1 = (ssg1 == 0.f) ? 1.f : rsqrtf(ssg1);

    // |dp*invp - dg*invg| = invp * |dp - (invg/invp)*dg|
    const __half nr0 = __float2half(-(invg0 / invp0));
    const __half nr1 = __float2half(-(invg1 / invp1));

    // ---- pass 2: re-read (cheap b64), 3 VALU per term ----
    __half a0A = __float2half(0.f), a0B = a0A, a1A = a0A, a1B = a0A;
    #pragma unroll
    for (int r = 0; r < REPEAT; ++r) {
        const int ho = hoff[r], wo = woff[r];
        const int pi = wo & 1;
        const int uo = (SPAN + ho) * QW + ((SPAN + wo - pi) >> 1);
        const uint2 vv = plane[pi][lanebase + uo];
        const __half2 d0 = __hsub2(c0, h2(vv.x));
        const __half2 d1 = __hsub2(c1, h2(vv.y));
        const __half s0 = __hfma(nr0, __high2half(d0), __low2half(d0));
        const __half s1 = __hfma(nr1, __high2half(d1), __low2half(d1));
        if (r & 1) { a0B = __hadd(a0B, __habs(s0)); a1B = __hadd(a1B, __habs(s1)); }
        else       { a0A = __hadd(a0A, __habs(s0)); a1A = __hadd(a1A, __habs(s1)); }
    }
    const float l0 = invp0 * (__half2float(a0A) + __half2float(a0B));
    const float l1 = invp1 * (__half2float(a1A) + __half2float(a1B));

    float lsum = (ok0 ? l0 : 0.f) + (ok1 ? l1 : 0.f);

    // ---- reduction: wave shuffle -> LDS -> one atomic per block ----
    #pragma unroll
    for (int o = 32; o > 0; o >>= 1) lsum += __shfl_down(lsum, o, 64);

    const int lane = t & 63;
    const int wid  = t >> 6;
    if (lane == 0) wsum[wid] = lsum;
    __syncthreads();

    if (t == 0) {
        const float s = wsum[0] + wsum[1] + wsum[2] + wsum[3];
        constexpr float scale = 1.0f / (4.0f * 472.0f * 472.0f * 90.0f);
        atomicAdd(out, s * scale);
    }
}

extern "C" void kernel_launch(void* const* d_in, const int* in_sizes, int n_in,
                              void* d_out, int out_size, void* d_ws, size_t ws_size,
                              hipStream_t stream) {
    const float* pred = (const float*)d_in[0];
    const float* gt   = (const float*)d_in[1];
    const int* hoff   = (const int*)d_in[2];
    const int* woff   = (const int*)d_in[3];
    float* out = (float*)d_out;

    // Harness poisons d_out once and never re-poisons between graph replays:
    // zero it on-stream every call (graph-capturable).
    hipMemsetAsync(out, 0, sizeof(float), stream);

    dim3 grid(8, 59, 4);   // (472/64, 472/8, B)
    rd_loss_kernel<<<grid, 256, 0, stream>>>(pred, gt, hoff, woff, out);
}

// Round 9
// 51.898 us; speedup vs baseline: 1.7018x; 1.7018x over previous
//
#include <hip/hip_runtime.h>
#include <hip/hip_fp16.h>

#define SPAN 20
#define REPEAT 90

// pred, gt: [4, 1, 512, 512] f32. h_offsets, w_offsets: [90] i32.
// out: scalar f32 = mean |l2norm(pred_rd) - l2norm(gt_rd)| over [B,Hb,Wb,R].

constexpr int W  = 512;
constexpr int Wb = 472;           // 512 - 2*SPAN
constexpr int TJ = 64;            // output tile width  (j)
constexpr int TI = 8;             // output tile height (i); 472/8 = 59 exact
constexpr int TW = TJ + 2 * SPAN; // 104 input tile width
constexpr int TH = TI + 2 * SPAN; // 48  input tile height
constexpr int QW = TW / 2;        // 52 pairs per row
constexpr int PLANE = TH * QW;    // 2496 8B elements per plane

typedef unsigned int u32;

static __device__ __forceinline__ u32 packpg(float p, float g) {
    const __half2 h = __floats2half2_rn(p, g);
    return __builtin_bit_cast(u32, h);
}
static __device__ __forceinline__ __half2 h2(u32 v) {
    return __builtin_bit_cast(__half2, v);
}

__global__ __launch_bounds__(256, 4) void rd_loss_kernel(
    const float* __restrict__ pred, const float* __restrict__ gt,
    const int* __restrict__ hoff, const int* __restrict__ woff,
    float* __restrict__ out)
{
    // Parity-duplicated pair planes: plane[pi] pair q = {x[2q+pi], x[2q+1+pi]}
    // with x = {p,g} packed as half2 in one u32. Any (hoff,woff) shift becomes
    // an ALIGNED contiguous ds_read_b64 from plane[woff&1]. 2*2496*8 = 39936 B.
    __shared__ uint2 plane[2][PLANE];
    __shared__ float wsum[4];

    const int t  = threadIdx.x;
    const int bx = blockIdx.x;    // 0..7   j-tile
    const int by = blockIdx.y;    // 0..58  i-tile
    const int b  = blockIdx.z;    // 0..3   batch
    const int I0 = by * TI;
    const int J0 = bx * TJ;

    const float* pb_ = pred + b * (W * W);
    const float* gb_ = gt   + b * (W * W);

    // ---- stage both planes (rows always in range; cols clamped to 510,
    //      clamped junk only feeds masked-out pixels) ----
    for (int e = t; e < PLANE; e += 256) {
        const int row = e / QW;           // magic-mul div
        const int q   = e - row * QW;
        const int gr  = I0 + row;                       // <= 511 always
        int c0 = J0 + 2 * q;  c0 = c0 < 510 ? c0 : 510; // even -> float2 ok
        int c2 = c0 + 2;      c2 = c2 < 510 ? c2 : 510;
        const float2 pLo = *(const float2*)(pb_ + gr * W + c0);
        const float2 gLo = *(const float2*)(gb_ + gr * W + c0);
        const float2 pHi = *(const float2*)(pb_ + gr * W + c2);
        const float2 gHi = *(const float2*)(gb_ + gr * W + c2);
        const u32 h0 = packpg(pLo.x, gLo.x);   // x[2q]
        const u32 h1 = packpg(pLo.y, gLo.y);   // x[2q+1]
        const u32 hx = packpg(pHi.x, gHi.x);   // x[2q+2]
        plane[0][e] = make_uint2(h0, h1);
        plane[1][e] = make_uint2(h1, hx);
    }
    __syncthreads();

    // ---- 2 pixels per thread: (row, 2*jp) and (row, 2*jp+1) ----
    const int jp  = t & 31;               // pair 0..31
    const int row = t >> 5;               // 0..7
    const bool ok0 = (J0 + 2 * jp)     < Wb;
    const bool ok1 = (J0 + 2 * jp + 1) < Wb;

    const int lanebase = row * QW + jp;   // per-lane element index part
    const uint2 cc = plane[0][(SPAN + row) * QW + (SPAN / 2 + jp)];
    const __half2 c0 = h2(cc.x), c1 = h2(cc.y);

    // ---- pass 1: packed sum-of-squares, even/odd split accumulators ----
    __half2 sA0 = __floats2half2_rn(0.f, 0.f), sB0 = sA0;
    __half2 sA1 = sA0, sB1 = sA0;
    #pragma unroll
    for (int r = 0; r < REPEAT; ++r) {
        const int ho = hoff[r], wo = woff[r];          // uniform (s_load)
        const int pi = wo & 1;
        const int uo = (SPAN + ho) * QW + ((SPAN + wo - pi) >> 1);
        const uint2 vv = plane[pi][lanebase + uo];     // aligned b64
        const __half2 d0 = __hsub2(c0, h2(vv.x));
        const __half2 d1 = __hsub2(c1, h2(vv.y));
        if (r & 1) { sB0 = __hfma2(d0, d0, sB0); sB1 = __hfma2(d1, d1, sB1); }
        else       { sA0 = __hfma2(d0, d0, sA0); sA1 = __hfma2(d1, d1, sA1); }
    }

    // ---- CSE firewall: rounds 7/8 the compiler kept all 90 uint2 LDS loads
    //      live across the rsqrt to reuse them in pass 2 -> 64 dwords/thread
    //      spilled to scratch -> 124 MB of HBM scratch traffic per launch.
    //      A memory clobber forces pass 2 to re-issue its (cheap) ds_reads.
    asm volatile("" ::: "memory");

    const float ssp0 = __half2float(__low2half(sA0))  + __half2float(__low2half(sB0));
    const float ssg0 = __half2float(__high2half(sA0)) + __half2float(__high2half(sB0));
    const float ssp1 = __half2float(__low2half(sA1))  + __half2float(__low2half(sB1));
    const float ssg1 = __half2float(__high2half(sA1)) + __half2float(__high2half(sB1));

    const float invp0 = (ssp0 == 0.f) ? 1.f : rsqrtf(ssp0);
    const float invg0 = (ssg0 == 0.f) ? 1.f : rsqrtf(ssg0);
    const float invp1 = (ssp1 == 0.f) ? 1.f : rsqrtf(ssp1);
    const float invg1 = (ssg1 == 0.f) ? 1.f : rsqrtf(ssg1);

    // |dp*invp - dg*invg| = invp * |dp - (invg/invp)*dg|
    const __half nr0 = __float2half(-(invg0 / invp0));
    const __half nr1 = __float2half(-(invg1 / invp1));

    // ---- pass 2: re-read (cheap b64), 3 VALU per term ----
    __half a0A = __float2half(0.f), a0B = a0A, a1A = a0A, a1B = a0A;
    #pragma unroll
    for (int r = 0; r < REPEAT; ++r) {
        const int ho = hoff[r], wo = woff[r];
        const int pi = wo & 1;
        const int uo = (SPAN + ho) * QW + ((SPAN + wo - pi) >> 1);
        const uint2 vv = plane[pi][lanebase + uo];
        const __half2 d0 = __hsub2(c0, h2(vv.x));
        const __half2 d1 = __hsub2(c1, h2(vv.y));
        const __half s0 = __hfma(nr0, __high2half(d0), __low2half(d0));
        const __half s1 = __hfma(nr1, __high2half(d1), __low2half(d1));
        if (r & 1) { a0B = __hadd(a0B, __habs(s0)); a1B = __hadd(a1B, __habs(s1)); }
        else       { a0A = __hadd(a0A, __habs(s0)); a1A = __hadd(a1A, __habs(s1)); }
    }
    const float l0 = invp0 * (__half2float(a0A) + __half2float(a0B));
    const float l1 = invp1 * (__half2float(a1A) + __half2float(a1B));

    float lsum = (ok0 ? l0 : 0.f) + (ok1 ? l1 : 0.f);

    // ---- reduction: wave shuffle -> LDS -> one atomic per block ----
    #pragma unroll
    for (int o = 32; o > 0; o >>= 1) lsum += __shfl_down(lsum, o, 64);

    const int lane = t & 63;
    const int wid  = t >> 6;
    if (lane == 0) wsum[wid] = lsum;
    __syncthreads();

    if (t == 0) {
        const float s = wsum[0] + wsum[1] + wsum[2] + wsum[3];
        constexpr float scale = 1.0f / (4.0f * 472.0f * 472.0f * 90.0f);
        atomicAdd(out, s * scale);
    }
}

extern "C" void kernel_launch(void* const* d_in, const int* in_sizes, int n_in,
                              void* d_out, int out_size, void* d_ws, size_t ws_size,
                              hipStream_t stream) {
    const float* pred = (const float*)d_in[0];
    const float* gt   = (const float*)d_in[1];
    const int* hoff   = (const int*)d_in[2];
    const int* woff   = (const int*)d_in[3];
    float* out = (float*)d_out;

    // Harness poisons d_out once and never re-poisons between graph replays:
    // zero it on-stream every call (graph-capturable).
    hipMemsetAsync(out, 0, sizeof(float), stream);

    dim3 grid(8, 59, 4);   // (472/64, 472/8, B)
    rd_loss_kernel<<<grid, 256, 0, stream>>>(pred, gt, hoff, woff, out);
}

// Round 10
// 50.946 us; speedup vs baseline: 1.7336x; 1.0187x over previous
//
#include <hip/hip_runtime.h>
#include <hip/hip_fp16.h>

#define SPAN 20
#define REPEAT 90

// pred, gt: [4, 1, 512, 512] f32. h_offsets, w_offsets: [90] i32.
// out: scalar f32 = mean |l2norm(pred_rd) - l2norm(gt_rd)| over [B,Hb,Wb,R].

constexpr int W  = 512;
constexpr int Wb = 472;           // 512 - 2*SPAN
constexpr int TJ = 64;            // output tile width  (j)
constexpr int TI = 8;             // output tile height (i); 472/8 = 59 exact
constexpr int TW = TJ + 2 * SPAN; // 104 input tile width
constexpr int TH = TI + 2 * SPAN; // 48  input tile height
constexpr int QW = TW / 2;        // 52 dword-pairs per row
constexpr int NPAIR = TH * QW;    // 2496 pairs

typedef unsigned int u32;

static __device__ __forceinline__ u32 packpg(float p, float g) {
    return __builtin_bit_cast(u32, __floats2half2_rn(p, g));
}
static __device__ __forceinline__ __half2 h2(u32 v) {
    return __builtin_bit_cast(__half2, v);
}

__global__ __launch_bounds__(256, 8) void rd_loss_kernel(
    const float* __restrict__ pred, const float* __restrict__ gt,
    const int* __restrict__ hoff, const int* __restrict__ woff,
    float* __restrict__ out)
{
    // SINGLE pg-packed plane (no parity duplication): tile[i*TW+j] = {p,g} as
    // half2 in one u32. A thread's 2 adjacent-j reads are tile[a], tile[a+1]
    // -> SILoadStoreOptimizer merges into ONE ds_read2_b32 (no alignment
    // needed, unlike b64). 48*104*4 = 19968 B -> 8 blocks/CU = 32 waves/CU.
    __shared__ u32 tile[TH * TW];
    __shared__ float wsum[4];

    const int t  = threadIdx.x;
    const int bx = blockIdx.x;    // 0..7   j-tile
    const int by = blockIdx.y;    // 0..58  i-tile
    const int b  = blockIdx.z;    // 0..3   batch
    const int I0 = by * TI;
    const int J0 = bx * TJ;

    const float* pb_ = pred + b * (W * W);
    const float* gb_ = gt   + b * (W * W);

    // ---- stage: each iter converts one even-aligned dword pair ----
    for (int e = t; e < NPAIR; e += 256) {
        const int row = e / QW;                          // magic-mul div
        const int q   = e - row * QW;
        const int gr  = I0 + row;                        // <= 511 always
        int gc = J0 + 2 * q; gc = gc < 510 ? gc : 510;   // even -> float2 ok
        const float2 pv = *(const float2*)(pb_ + gr * W + gc);
        const float2 gv = *(const float2*)(gb_ + gr * W + gc);
        // dword index 2e is even -> aligned ds_write_b64
        *(uint2*)&tile[2 * e] = make_uint2(packpg(pv.x, gv.x),
                                           packpg(pv.y, gv.y));
    }
    __syncthreads();

    // ---- 2 adjacent-j pixels per thread: (row, 2jp) and (row, 2jp+1) ----
    const int jp  = t & 31;               // pair 0..31
    const int row = t >> 5;               // 0..7
    const bool ok0 = (J0 + 2 * jp)     < Wb;
    const bool ok1 = (J0 + 2 * jp + 1) < Wb;

    const int cbase = (SPAN + row) * TW + (SPAN + 2 * jp);
    const __half2 c0 = h2(tile[cbase]);
    const __half2 c1 = h2(tile[cbase + 1]);

    // ---- pass 1: packed {ssp,ssg} sums, even/odd split accumulators ----
    __half2 sA0 = __floats2half2_rn(0.f, 0.f), sB0 = sA0;
    __half2 sA1 = sA0, sB1 = sA0;
    #pragma unroll
    for (int r = 0; r < REPEAT; ++r) {
        const int off = hoff[r] * TW + woff[r];          // uniform (s_load)
        const int a   = cbase + off;                     // 1 v_add
        const u32 v0 = tile[a];                          // ds_read2_b32
        const u32 v1 = tile[a + 1];                      //   (merged pair)
        const __half2 d0 = __hsub2(c0, h2(v0));
        const __half2 d1 = __hsub2(c1, h2(v1));
        if (r & 1) { sB0 = __hfma2(d0, d0, sB0); sB1 = __hfma2(d1, d1, sB1); }
        else       { sA0 = __hfma2(d0, d0, sA0); sA1 = __hfma2(d1, d1, sA1); }
    }

    // ---- CSE firewall (rounds 7/8): stops the compiler from keeping all
    //      180 dwords of LDS loads live across the rsqrt (-> scratch spill).
    asm volatile("" ::: "memory");

    const float ssp0 = __half2float(__low2half(sA0))  + __half2float(__low2half(sB0));
    const float ssg0 = __half2float(__high2half(sA0)) + __half2float(__high2half(sB0));
    const float ssp1 = __half2float(__low2half(sA1))  + __half2float(__low2half(sB1));
    const float ssg1 = __half2float(__high2half(sA1)) + __half2float(__high2half(sB1));

    const float invp0 = (ssp0 == 0.f) ? 1.f : rsqrtf(ssp0);
    const float invg0 = (ssg0 == 0.f) ? 1.f : rsqrtf(ssg0);
    const float invp1 = (ssp1 == 0.f) ? 1.f : rsqrtf(ssp1);
    const float invg1 = (ssg1 == 0.f) ? 1.f : rsqrtf(ssg1);

    // |dp*invp - dg*invg| = invp * |dp - (invg/invp)*dg|
    const __half nr0 = __float2half(-(invg0 / invp0));
    const __half nr1 = __float2half(-(invg1 / invp1));

    // ---- pass 2: re-read (cheap ds_read2), op_sel fma + abs-add ----
    __half a0A = __float2half(0.f), a0B = a0A, a1A = a0A, a1B = a0A;
    #pragma unroll
    for (int r = 0; r < REPEAT; ++r) {
        const int off = hoff[r] * TW + woff[r];
        const int a   = cbase + off;
        const u32 v0 = tile[a];
        const u32 v1 = tile[a + 1];
        const __half2 d0 = __hsub2(c0, h2(v0));
        const __half2 d1 = __hsub2(c1, h2(v1));
        const __half s0 = __hfma(nr0, __high2half(d0), __low2half(d0));
        const __half s1 = __hfma(nr1, __high2half(d1), __low2half(d1));
        if (r & 1) { a0B = __hadd(a0B, __habs(s0)); a1B = __hadd(a1B, __habs(s1)); }
        else       { a0A = __hadd(a0A, __habs(s0)); a1A = __hadd(a1A, __habs(s1)); }
    }
    const float l0 = invp0 * (__half2float(a0A) + __half2float(a0B));
    const float l1 = invp1 * (__half2float(a1A) + __half2float(a1B));

    float lsum = (ok0 ? l0 : 0.f) + (ok1 ? l1 : 0.f);

    // ---- reduction: wave shuffle -> LDS -> one atomic per block ----
    #pragma unroll
    for (int o = 32; o > 0; o >>= 1) lsum += __shfl_down(lsum, o, 64);

    const int lane = t & 63;
    const int wid  = t >> 6;
    if (lane == 0) wsum[wid] = lsum;
    __syncthreads();

    if (t == 0) {
        const float s = wsum[0] + wsum[1] + wsum[2] + wsum[3];
        constexpr float scale = 1.0f / (4.0f * 472.0f * 472.0f * 90.0f);
        atomicAdd(out, s * scale);
    }
}

extern "C" void kernel_launch(void* const* d_in, const int* in_sizes, int n_in,
                              void* d_out, int out_size, void* d_ws, size_t ws_size,
                              hipStream_t stream) {
    const float* pred = (const float*)d_in[0];
    const float* gt   = (const float*)d_in[1];
    const int* hoff   = (const int*)d_in[2];
    const int* woff   = (const int*)d_in[3];
    float* out = (float*)d_out;

    // Harness poisons d_out once and never re-poisons between graph replays:
    // zero it on-stream every call (graph-capturable).
    hipMemsetAsync(out, 0, sizeof(float), stream);

    dim3 grid(8, 59, 4);   // (472/64, 472/8, B)
    rd_loss_kernel<<<grid, 256, 0, stream>>>(pred, gt, hoff, woff, out);
}

// Round 11
// 49.353 us; speedup vs baseline: 1.7896x; 1.0323x over previous
//
#include <hip/hip_runtime.h>
#include <hip/hip_fp16.h>

#define SPAN 20
#define REPEAT 90

// pred, gt: [4, 1, 512, 512] f32. h_offsets, w_offsets: [90] i32.
// out: scalar f32 = mean |l2norm(pred_rd) - l2norm(gt_rd)| over [B,Hb,Wb,R].

constexpr int W  = 512;
constexpr int Wb = 472;           // 512 - 2*SPAN
constexpr int TJ = 64;            // output tile width  (j)
constexpr int TI = 8;             // output tile height (i); 472/8 = 59 exact
constexpr int TW = TJ + 2 * SPAN; // 104 input tile width
constexpr int TH = TI + 2 * SPAN; // 48  input tile height
constexpr int QW = TW / 2;        // 52 dword-pairs per row (staging)
constexpr int NPAIR = TH * QW;    // 2496 pairs

typedef unsigned int u32;

static __device__ __forceinline__ u32 packpg(float p, float g) {
    return __builtin_bit_cast(u32, __floats2half2_rn(p, g));
}
static __device__ __forceinline__ __half2 h2(u32 v) {
    return __builtin_bit_cast(__half2, v);
}

__global__ __launch_bounds__(256, 4) void rd_loss_kernel(
    const float* __restrict__ pred, const float* __restrict__ gt,
    const int* __restrict__ hoff, const int* __restrict__ woff,
    float* __restrict__ out)
{
    // Single pg-packed plane: tile[i*TW+j] = {p,g} half2 in one u32.
    // Thread owns (row, jj) and (row, jj+32), jj = t&31: lane stride is 4B
    // (dword-consecutive -> 2 lanes/bank = FREE; round 10's 2*jp stride-8B
    // mapping was a 4-way conflict, 5.4M events). The +32 pixel rides the
    // same ds_read2_b32 via its second dword-offset immediate.
    __shared__ u32 tile[TH * TW];     // 19968 B -> 8 blocks/CU by LDS
    __shared__ float wsum[4];

    const int t  = threadIdx.x;
    const int bx = blockIdx.x;    // 0..7   j-tile
    const int by = blockIdx.y;    // 0..58  i-tile
    const int b  = blockIdx.z;    // 0..3   batch
    const int I0 = by * TI;
    const int J0 = bx * TJ;

    const float* pb_ = pred + b * (W * W);
    const float* gb_ = gt   + b * (W * W);

    // ---- stage: one even-aligned dword pair per iter ----
    for (int e = t; e < NPAIR; e += 256) {
        const int row = e / QW;                          // magic-mul div
        const int q   = e - row * QW;
        const int gr  = I0 + row;                        // <= 511 always
        int gc = J0 + 2 * q; gc = gc < 510 ? gc : 510;   // even -> float2 ok
        const float2 pv = *(const float2*)(pb_ + gr * W + gc);
        const float2 gv = *(const float2*)(gb_ + gr * W + gc);
        *(uint2*)&tile[2 * e] = make_uint2(packpg(pv.x, gv.x),
                                           packpg(pv.y, gv.y));
    }
    __syncthreads();

    // ---- 2 pixels per thread: (row, jj) and (row, jj+32) ----
    const int jj  = t & 31;
    const int row = t >> 5;               // 0..7
    const bool ok0 = (J0 + jj)      < Wb;
    const bool ok1 = (J0 + jj + 32) < Wb;

    const int cbase = (SPAN + row) * TW + (SPAN + jj);
    const __half2 c0 = h2(tile[cbase]);
    const __half2 c1 = h2(tile[cbase + 32]);

    // ---- pass 1: packed {ssp,ssg} sums, even/odd split accumulators ----
    __half2 sA0 = __floats2half2_rn(0.f, 0.f), sB0 = sA0;
    __half2 sA1 = sA0, sB1 = sA0;
    #pragma unroll
    for (int r = 0; r < REPEAT; ++r) {
        const int off = hoff[r] * TW + woff[r];          // uniform (s_load)
        const int a   = cbase + off;                     // 1 v_add
        const u32 v0 = tile[a];                          // ds_read2_b32
        const u32 v1 = tile[a + 32];                     //   offset1:+32
        const __half2 d0 = __hsub2(c0, h2(v0));
        const __half2 d1 = __hsub2(c1, h2(v1));
        if (r & 1) { sB0 = __hfma2(d0, d0, sB0); sB1 = __hfma2(d1, d1, sB1); }
        else       { sA0 = __hfma2(d0, d0, sA0); sA1 = __hfma2(d1, d1, sA1); }
    }

    // ---- CSE firewall (rounds 7/8): stops the compiler from keeping all
    //      180 dwords of LDS loads live across the rsqrt (-> scratch spill).
    asm volatile("" ::: "memory");

    const float ssp0 = __half2float(__low2half(sA0))  + __half2float(__low2half(sB0));
    const float ssg0 = __half2float(__high2half(sA0)) + __half2float(__high2half(sB0));
    const float ssp1 = __half2float(__low2half(sA1))  + __half2float(__low2half(sB1));
    const float ssg1 = __half2float(__high2half(sA1)) + __half2float(__high2half(sB1));

    const float invp0 = (ssp0 == 0.f) ? 1.f : rsqrtf(ssp0);
    const float invg0 = (ssg0 == 0.f) ? 1.f : rsqrtf(ssg0);
    const float invp1 = (ssp1 == 0.f) ? 1.f : rsqrtf(ssp1);
    const float invg1 = (ssg1 == 0.f) ? 1.f : rsqrtf(ssg1);

    // |dp*invp - dg*invg| = invp * |dp - (invg/invp)*dg|
    const __half nr0 = __float2half(-(invg0 / invp0));
    const __half nr1 = __float2half(-(invg1 / invp1));

    // ---- pass 2: re-read (cheap ds_read2), op_sel fma + abs-add ----
    __half a0A = __float2half(0.f), a0B = a0A, a1A = a0A, a1B = a0A;
    #pragma unroll
    for (int r = 0; r < REPEAT; ++r) {
        const int off = hoff[r] * TW + woff[r];
        const int a   = cbase + off;
        const u32 v0 = tile[a];
        const u32 v1 = tile[a + 32];
        const __half2 d0 = __hsub2(c0, h2(v0));
        const __half2 d1 = __hsub2(c1, h2(v1));
        const __half s0 = __hfma(nr0, __high2half(d0), __low2half(d0));
        const __half s1 = __hfma(nr1, __high2half(d1), __low2half(d1));
        if (r & 1) { a0B = __hadd(a0B, __habs(s0)); a1B = __hadd(a1B, __habs(s1)); }
        else       { a0A = __hadd(a0A, __habs(s0)); a1A = __hadd(a1A, __habs(s1)); }
    }
    const float l0 = invp0 * (__half2float(a0A) + __half2float(a0B));
    const float l1 = invp1 * (__half2float(a1A) + __half2float(a1B));

    float lsum = (ok0 ? l0 : 0.f) + (ok1 ? l1 : 0.f);

    // ---- reduction: wave shuffle -> LDS -> one atomic per block ----
    #pragma unroll
    for (int o = 32; o > 0; o >>= 1) lsum += __shfl_down(lsum, o, 64);

    const int lane = t & 63;
    const int wid  = t >> 6;
    if (lane == 0) wsum[wid] = lsum;
    __syncthreads();

    if (t == 0) {
        const float s = wsum[0] + wsum[1] + wsum[2] + wsum[3];
        constexpr float scale = 1.0f / (4.0f * 472.0f * 472.0f * 90.0f);
        atomicAdd(out, s * scale);
    }
}

extern "C" void kernel_launch(void* const* d_in, const int* in_sizes, int n_in,
                              void* d_out, int out_size, void* d_ws, size_t ws_size,
                              hipStream_t stream) {
    const float* pred = (const float*)d_in[0];
    const float* gt   = (const float*)d_in[1];
    const int* hoff   = (const int*)d_in[2];
    const int* woff   = (const int*)d_in[3];
    float* out = (float*)d_out;

    // Harness poisons d_out once and never re-poisons between graph replays:
    // zero it on-stream every call (graph-capturable).
    hipMemsetAsync(out, 0, sizeof(float), stream);

    dim3 grid(8, 59, 4);   // (472/64, 472/8, B)
    rd_loss_kernel<<<grid, 256, 0, stream>>>(pred, gt, hoff, woff, out);
}

// Round 12
// 46.801 us; speedup vs baseline: 1.8871x; 1.0545x over previous
//
#include <hip/hip_runtime.h>
#include <hip/hip_fp16.h>

#define SPAN 20
#define REPEAT 90

// pred, gt: [4, 1, 512, 512] f32. h_offsets, w_offsets: [90] i32.
// out: scalar f32 = mean |l2norm(pred_rd) - l2norm(gt_rd)| over [B,Hb,Wb,R].

constexpr int W  = 512;
constexpr int Wb = 472;           // 512 - 2*SPAN
constexpr int TJ = 64;            // output tile width  (j)
constexpr int TI = 8;             // output tile height (i); 472/8 = 59 exact
constexpr int TW = TJ + 2 * SPAN; // 104 input tile width
constexpr int TH = TI + 2 * SPAN; // 48  input tile height
constexpr int QW = TW / 2;        // 52 dword-pairs per row (staging)
constexpr int NPAIR = TH * QW;    // 2496 pairs
constexpr int PF = 8;             // prefetch ring depth

typedef unsigned int u32;

static __device__ __forceinline__ u32 packpg(float p, float g) {
    return __builtin_bit_cast(u32, __floats2half2_rn(p, g));
}
static __device__ __forceinline__ __half2 h2(u32 v) {
    return __builtin_bit_cast(__half2, v);
}

__global__ __launch_bounds__(256, 4) void rd_loss_kernel(
    const float* __restrict__ pred, const float* __restrict__ gt,
    const int* __restrict__ hoff, const int* __restrict__ woff,
    float* __restrict__ out)
{
    // Single pg-packed plane: tile[i*TW+j] = {p,g} half2 in one u32.
    // Thread owns (row, jj) and (row, jj+32), jj = t&31: 4B lane stride
    // (2 lanes/bank = free); +32 pixel rides the same ds_read2_b32.
    __shared__ u32 tile[TH * TW];     // 19968 B -> 8 blocks/CU by LDS
    __shared__ float wsum[4];

    const int t  = threadIdx.x;
    const int bx = blockIdx.x;    // 0..7   j-tile
    const int by = blockIdx.y;    // 0..58  i-tile
    const int b  = blockIdx.z;    // 0..3   batch
    const int I0 = by * TI;
    const int J0 = bx * TJ;

    const float* pb_ = pred + b * (W * W);
    const float* gb_ = gt   + b * (W * W);

    // ---- stage: one even-aligned dword pair per iter ----
    for (int e = t; e < NPAIR; e += 256) {
        const int row = e / QW;                          // magic-mul div
        const int q   = e - row * QW;
        const int gr  = I0 + row;                        // <= 511 always
        int gc = J0 + 2 * q; gc = gc < 510 ? gc : 510;   // even -> float2 ok
        const float2 pv = *(const float2*)(pb_ + gr * W + gc);
        const float2 gv = *(const float2*)(gb_ + gr * W + gc);
        *(uint2*)&tile[2 * e] = make_uint2(packpg(pv.x, gv.x),
                                           packpg(pv.y, gv.y));
    }
    __syncthreads();

    // ---- 2 pixels per thread: (row, jj) and (row, jj+32) ----
    const int jj  = t & 31;
    const int row = t >> 5;               // 0..7
    const bool ok0 = (J0 + jj)      < Wb;
    const bool ok1 = (J0 + jj + 32) < Wb;

    const int cbase = (SPAN + row) * TW + (SPAN + jj);
    const __half2 c0 = h2(tile[cbase]);
    const __half2 c1 = h2(tile[cbase + 32]);

    // ================= pass 1: sum-of-squares, PF-deep ring ==============
    // Ring slots statically indexed (r%PF with literal r after full unroll):
    // consume slot, then refill it with iteration r+PF -> 8 ds_read2 always
    // in flight -> waits become lgkmcnt(~PF-1) instead of per-iter drains.
    u32 v0[PF], v1[PF];
    #pragma unroll
    for (int k = 0; k < PF; ++k) {
        const int a = cbase + (hoff[k] * TW + woff[k]);
        v0[k] = tile[a];                                 // ds_read2_b32
        v1[k] = tile[a + 32];
    }

    __half2 sA0 = __floats2half2_rn(0.f, 0.f), sB0 = sA0;
    __half2 sA1 = sA0, sB1 = sA0;
    #pragma unroll
    for (int r = 0; r < REPEAT; ++r) {
        const int slot = r % PF;                         // literal after unroll
        const __half2 d0 = __hsub2(c0, h2(v0[slot]));
        const __half2 d1 = __hsub2(c1, h2(v1[slot]));
        if (r & 1) { sB0 = __hfma2(d0, d0, sB0); sB1 = __hfma2(d1, d1, sB1); }
        else       { sA0 = __hfma2(d0, d0, sA0); sA1 = __hfma2(d1, d1, sA1); }
        const int rn = r + PF;
        if (rn < REPEAT) {
            const int a = cbase + (hoff[rn] * TW + woff[rn]);
            v0[slot] = tile[a];
            v1[slot] = tile[a + 32];
        }
    }

    // ---- CSE firewall (rounds 7/8): stops the compiler from keeping all
    //      180 dwords of LDS loads live across the rsqrt (-> scratch spill).
    asm volatile("" ::: "memory");

    const float ssp0 = __half2float(__low2half(sA0))  + __half2float(__low2half(sB0));
    const float ssg0 = __half2float(__high2half(sA0)) + __half2float(__high2half(sB0));
    const float ssp1 = __half2float(__low2half(sA1))  + __half2float(__low2half(sB1));
    const float ssg1 = __half2float(__high2half(sA1)) + __half2float(__high2half(sB1));

    const float invp0 = (ssp0 == 0.f) ? 1.f : rsqrtf(ssp0);
    const float invg0 = (ssg0 == 0.f) ? 1.f : rsqrtf(ssg0);
    const float invp1 = (ssp1 == 0.f) ? 1.f : rsqrtf(ssp1);
    const float invg1 = (ssg1 == 0.f) ? 1.f : rsqrtf(ssg1);

    // |dp*invp - dg*invg| = invp * |dp - (invg/invp)*dg|
    const __half nr0 = __float2half(-(invg0 / invp0));
    const __half nr1 = __float2half(-(invg1 / invp1));

    // ================= pass 2: same PF-deep ring =========================
    #pragma unroll
    for (int k = 0; k < PF; ++k) {
        const int a = cbase + (hoff[k] * TW + woff[k]);
        v0[k] = tile[a];
        v1[k] = tile[a + 32];
    }

    __half a0A = __float2half(0.f), a0B = a0A, a1A = a0A, a1B = a0A;
    #pragma unroll
    for (int r = 0; r < REPEAT; ++r) {
        const int slot = r % PF;
        const __half2 d0 = __hsub2(c0, h2(v0[slot]));
        const __half2 d1 = __hsub2(c1, h2(v1[slot]));
        const __half s0 = __hfma(nr0, __high2half(d0), __low2half(d0));
        const __half s1 = __hfma(nr1, __high2half(d1), __low2half(d1));
        if (r & 1) { a0B = __hadd(a0B, __habs(s0)); a1B = __hadd(a1B, __habs(s1)); }
        else       { a0A = __hadd(a0A, __habs(s0)); a1A = __hadd(a1A, __habs(s1)); }
        const int rn = r + PF;
        if (rn < REPEAT) {
            const int a = cbase + (hoff[rn] * TW + woff[rn]);
            v0[slot] = tile[a];
            v1[slot] = tile[a + 32];
        }
    }
    const float l0 = invp0 * (__half2float(a0A) + __half2float(a0B));
    const float l1 = invp1 * (__half2float(a1A) + __half2float(a1B));

    float lsum = (ok0 ? l0 : 0.f) + (ok1 ? l1 : 0.f);

    // ---- reduction: wave shuffle -> LDS -> one atomic per block ----
    #pragma unroll
    for (int o = 32; o > 0; o >>= 1) lsum += __shfl_down(lsum, o, 64);

    const int lane = t & 63;
    const int wid  = t >> 6;
    if (lane == 0) wsum[wid] = lsum;
    __syncthreads();

    if (t == 0) {
        const float s = wsum[0] + wsum[1] + wsum[2] + wsum[3];
        constexpr float scale = 1.0f / (4.0f * 472.0f * 472.0f * 90.0f);
        atomicAdd(out, s * scale);
    }
}

extern "C" void kernel_launch(void* const* d_in, const int* in_sizes, int n_in,
                              void* d_out, int out_size, void* d_ws, size_t ws_size,
                              hipStream_t stream) {
    const float* pred = (const float*)d_in[0];
    const float* gt   = (const float*)d_in[1];
    const int* hoff   = (const int*)d_in[2];
    const int* woff   = (const int*)d_in[3];
    float* out = (float*)d_out;

    // Harness poisons d_out once and never re-poisons between graph replays:
    // zero it on-stream every call (graph-capturable).
    hipMemsetAsync(out, 0, sizeof(float), stream);

    dim3 grid(8, 59, 4);   // (472/64, 472/8, B)
    rd_loss_kernel<<<grid, 256, 0, stream>>>(pred, gt, hoff, woff, out);
}